// Round 1
// baseline (1087.077 us; speedup 1.0000x reference)
//
#include <hip/hip_runtime.h>
#include <cstdint>
#include <cstddef>

#define H_DIM 1024
#define F_DIM 4096
#define N_EXP 8
#define N_TOK 8192
#define NK_ASSIGN (N_TOK * 2)

typedef unsigned short u16;
typedef __attribute__((ext_vector_type(8))) short bf16x8;
typedef __attribute__((ext_vector_type(4))) float f32x4;

// RNE float -> bf16 bits (finite inputs only)
__device__ __forceinline__ u16 f2bf(float f) {
  unsigned int u = __float_as_uint(f);
  u += 0x7fffu + ((u >> 16) & 1u);
  return (u16)(u >> 16);
}

// async global->LDS, 16B per lane. lds ptr MUST be wave-uniform (HW adds lane*16).
__device__ __forceinline__ void load16(const u16* g, u16* l) {
  __builtin_amdgcn_global_load_lds(
      (const __attribute__((address_space(1))) void*)g,
      (__attribute__((address_space(3))) void*)l, 16, 0, 0);
}

// ---------------- router: fp32 logits, top-2, renormalized softmax gates ----
__global__ __launch_bounds__(256) void router_kernel(
    const float* __restrict__ x, const float* __restrict__ rw,
    const float* __restrict__ rb, int* __restrict__ topk_idx,
    float* __restrict__ topk_w, int* __restrict__ counts) {
  const int lane = threadIdx.x & 63;
  const int wid = threadIdx.x >> 6;
  const int t = blockIdx.x * 4 + wid;  // one wave per token
  const float4* xr = (const float4*)(x + (size_t)t * H_DIM);
  float acc[N_EXP];
#pragma unroll
  for (int e = 0; e < N_EXP; ++e) acc[e] = 0.f;
#pragma unroll
  for (int j = 0; j < 4; ++j) {
    float4 xv = xr[j * 64 + lane];
#pragma unroll
    for (int e = 0; e < N_EXP; ++e) {
      float4 wv = ((const float4*)(rw + e * H_DIM))[j * 64 + lane];
      acc[e] += xv.x * wv.x + xv.y * wv.y + xv.z * wv.z + xv.w * wv.w;
    }
  }
#pragma unroll
  for (int off = 32; off > 0; off >>= 1) {
#pragma unroll
    for (int e = 0; e < N_EXP; ++e) acc[e] += __shfl_xor(acc[e], off);
  }
  if (lane == 0) {
    float lg[N_EXP];
#pragma unroll
    for (int e = 0; e < N_EXP; ++e) lg[e] = acc[e] + rb[e];
    int i0 = 0;
    float b0 = lg[0];
#pragma unroll
    for (int e = 1; e < N_EXP; ++e)
      if (lg[e] > b0) { b0 = lg[e]; i0 = e; }  // strict > : lowest index wins ties (matches jax)
    int i1 = -1;
    float b1 = -3.4e38f;
#pragma unroll
    for (int e = 0; e < N_EXP; ++e)
      if (e != i0 && lg[e] > b1) { b1 = lg[e]; i1 = e; }
    // normalized top-2 softmax: w0 = p0/(p0+p1) = 1/(1+exp(l1-l0))
    float w0 = 1.f / (1.f + expf(b1 - b0));
    topk_idx[2 * t] = i0;
    topk_idx[2 * t + 1] = i1;
    topk_w[2 * t] = w0;
    topk_w[2 * t + 1] = 1.f - w0;
    atomicAdd(&counts[i0], 1);
    atomicAdd(&counts[i1], 1);
  }
}

// ---------------- tiny exclusive scan over 8 counts --------------------------
__global__ void scan_kernel(const int* __restrict__ counts,
                            int* __restrict__ offsets,
                            int* __restrict__ cursors) {
  if (threadIdx.x == 0) {
    int s = 0;
    for (int e = 0; e < N_EXP; ++e) {
      offsets[e] = s;
      s += counts[e];
      cursors[e] = 0;
    }
    offsets[N_EXP] = s;  // == 16384
  }
}

// ---------------- scatter token assignments into expert segments -------------
__global__ __launch_bounds__(256) void scatter_kernel(
    const int* __restrict__ topk_idx, const float* __restrict__ topk_w,
    const int* __restrict__ offsets, int* __restrict__ cursors,
    int* __restrict__ assign_token, float* __restrict__ assign_gate) {
  int t = blockIdx.x * 256 + threadIdx.x;
  if (t >= N_TOK) return;
#pragma unroll
  for (int k = 0; k < 2; ++k) {
    int e = topk_idx[2 * t + k];
    int pos = offsets[e] + atomicAdd(&cursors[e], 1);
    assign_token[pos] = t;
    assign_gate[pos] = topk_w[2 * t + k];
  }
}

// ---------------- fp32 [E][R][C] -> bf16 [E][C][R] (transpose + convert) -----
__global__ __launch_bounds__(256) void transpose_cvt(
    const float* __restrict__ in, u16* __restrict__ out, int R, int C) {
  __shared__ float tile[32][33];
  const int e = blockIdx.z;
  const float* ip = in + (size_t)e * R * C;
  u16* op = out + (size_t)e * R * C;
  const int c0 = blockIdx.x * 32, r0 = blockIdx.y * 32;
  const int tx = threadIdx.x & 31, ty = threadIdx.x >> 5;
#pragma unroll
  for (int i = 0; i < 32; i += 8)
    tile[ty + i][tx] = ip[(size_t)(r0 + ty + i) * C + (c0 + tx)];
  __syncthreads();
#pragma unroll
  for (int i = 0; i < 32; i += 8)
    op[(size_t)(c0 + ty + i) * R + (r0 + tx)] = f2bf(tile[tx][ty + i]);
}

// ---------------- gather tokens -> compacted bf16 A ([slot][H]) --------------
__global__ __launch_bounds__(256) void gather_kernel(
    const float* __restrict__ x, const int* __restrict__ assign_token,
    u16* __restrict__ xg) {
  const int lane = threadIdx.x & 63;
  const int s = blockIdx.x * 4 + (threadIdx.x >> 6);  // one wave per slot
  const int t = assign_token[s];
  const float4* xr = (const float4*)(x + (size_t)t * H_DIM);
  u16* o = xg + (size_t)s * H_DIM;
#pragma unroll
  for (int j = 0; j < 4; ++j) {
    float4 v = xr[j * 64 + lane];
    ushort4 u;
    u.x = f2bf(v.x); u.y = f2bf(v.y); u.z = f2bf(v.z); u.w = f2bf(v.w);
    *(ushort4*)(o + (size_t)(j * 64 + lane) * 4) = u;
  }
}

// ---------------- grouped GEMM: C[M][N] = A[M][K] * B[N][K]^T ---------------
// 128x128 tile, BK=32, 4 waves, each wave 4x4 of 16x16x32 bf16 MFMA.
// FIRST:  A=xg, B=w1b, epilogue = exact gelu -> bf16 store to h
// !FIRST: A=h,  B=w2b, epilogue = *gate, fp32 atomicAdd into out[token]
template <int LDA, int LDB, int LDC, int KITERS, bool FIRST>
__global__ __launch_bounds__(256) void moe_gemm(
    const u16* __restrict__ Abase, const u16* __restrict__ Bbase,
    u16* __restrict__ hout, float* __restrict__ yout,
    const int* __restrict__ offsets, const int* __restrict__ assign_token,
    const float* __restrict__ assign_gate) {
  __shared__ __align__(16) u16 As[128 * 32];
  __shared__ __align__(16) u16 Bs[128 * 32];
  const int e = blockIdx.z;
  const int row0 = offsets[e];
  const int cnt = offsets[e + 1] - row0;
  const int mbase = blockIdx.y * 128;
  if (mbase >= cnt) return;  // block-uniform early exit (grid covers worst case)
  const int mrem = cnt - mbase;
  const int n0 = blockIdx.x * 128;
  const int tid = threadIdx.x;
  const int lane = tid & 63;
  const int wid = tid >> 6;
  const int wm = wid & 1, wn = wid >> 1;
  const u16* A = Abase + (size_t)(row0 + mbase) * LDA;
  const u16* B = Bbase + (size_t)e * ((size_t)H_DIM * F_DIM);
  const int row16 = lane & 15, quad = lane >> 4;
  const int srow = lane >> 2;        // staging: row within 16-row chunk
  const int scol = (lane & 3) * 8;   // staging: k-col (elements)

  f32x4 acc[4][4];
#pragma unroll
  for (int i = 0; i < 4; ++i)
#pragma unroll
    for (int j = 0; j < 4; ++j)
#pragma unroll
      for (int r = 0; r < 4; ++r) acc[i][j][r] = 0.f;

  for (int kt = 0; kt < KITERS; ++kt) {
    const int k0 = kt * 32;
#pragma unroll
    for (int i = 0; i < 2; ++i) {
      const int c = wid * 2 + i;           // chunk 0..7 (16 rows x 64B each)
      const int r = c * 16 + srow;
      const int ra = min(r, mrem - 1);     // clamp: stay inside valid A rows
      load16(A + (size_t)ra * LDA + (k0 + scol), &As[c * 512]);
      load16(B + (size_t)(n0 + r) * LDB + (k0 + scol), &Bs[c * 512]);
    }
    __syncthreads();  // drains vmcnt -> LDS tiles complete
    bf16x8 av[4], bv[4];
#pragma unroll
    for (int mi = 0; mi < 4; ++mi)
      av[mi] = *(const bf16x8*)&As[(wm * 64 + mi * 16 + row16) * 32 + quad * 8];
#pragma unroll
    for (int ni = 0; ni < 4; ++ni)
      bv[ni] = *(const bf16x8*)&Bs[(wn * 64 + ni * 16 + row16) * 32 + quad * 8];
#pragma unroll
    for (int mi = 0; mi < 4; ++mi)
#pragma unroll
      for (int ni = 0; ni < 4; ++ni)
        acc[mi][ni] =
            __builtin_amdgcn_mfma_f32_16x16x32_bf16(av[mi], bv[ni], acc[mi][ni], 0, 0, 0);
    __syncthreads();
  }

  // C/D layout: col = lane&15 (n), row = quad*4 + reg (m)  [guide §3, m89/m91]
  if (FIRST) {
    u16* Cp = hout + (size_t)(row0 + mbase) * LDC + n0;
#pragma unroll
    for (int mi = 0; mi < 4; ++mi) {
#pragma unroll
      for (int r = 0; r < 4; ++r) {
        const int lm = wm * 64 + mi * 16 + quad * 4 + r;
        if (lm < mrem) {
#pragma unroll
          for (int ni = 0; ni < 4; ++ni) {
            float v = acc[mi][ni][r];
            v = 0.5f * v * (1.f + erff(v * 0.70710678118654752f));  // exact gelu
            Cp[(size_t)lm * LDC + (wn * 64 + ni * 16 + row16)] = f2bf(v);
          }
        }
      }
    }
  } else {
#pragma unroll
    for (int mi = 0; mi < 4; ++mi) {
#pragma unroll
      for (int r = 0; r < 4; ++r) {
        const int lm = wm * 64 + mi * 16 + quad * 4 + r;
        if (lm < mrem) {
          const int slot = row0 + mbase + lm;
          const int t = assign_token[slot];
          const float g = assign_gate[slot];
          float* orow = yout + (size_t)t * LDC + n0;
#pragma unroll
          for (int ni = 0; ni < 4; ++ni)
            atomicAdd(&orow[wn * 64 + ni * 16 + row16], acc[mi][ni][r] * g);
        }
      }
    }
  }
}

extern "C" void kernel_launch(void* const* d_in, const int* in_sizes, int n_in,
                              void* d_out, int out_size, void* d_ws, size_t ws_size,
                              hipStream_t stream) {
  const float* x = (const float*)d_in[0];
  const float* rw = (const float*)d_in[1];
  const float* rb = (const float*)d_in[2];
  const float* w1 = (const float*)d_in[3];
  const float* w2 = (const float*)d_in[4];
  float* out = (float*)d_out;

  char* ws = (char*)d_ws;
  // workspace layout (~302.3 MB total)
  u16* w1b = (u16*)(ws);                        // [E][F][H] bf16   67,108,864 B
  u16* w2b = (u16*)(ws + 67108864);             // [E][H][F] bf16   67,108,864 B
  u16* xg = (u16*)(ws + 134217728);             // [16384][H] bf16  33,554,432 B
  u16* h = (u16*)(ws + 167772160);              // [16384][F] bf16 134,217,728 B
  char* meta = ws + 301989888;
  int* counts = (int*)(meta + 0);
  int* cursors = (int*)(meta + 32);
  int* offsets = (int*)(meta + 64);             // 9 ints
  int* topk_idx = (int*)(meta + 128);           // 16384 ints
  float* topk_w = (float*)(meta + 128 + 65536);
  int* assign_token = (int*)(meta + 128 + 131072);
  float* assign_gate = (float*)(meta + 128 + 196608);

  hipMemsetAsync(counts, 0, 64, stream);  // counts + cursors
  hipMemsetAsync(d_out, 0, (size_t)out_size * sizeof(float), stream);

  router_kernel<<<N_TOK / 4, 256, 0, stream>>>(x, rw, rb, topk_idx, topk_w, counts);
  scan_kernel<<<1, 64, 0, stream>>>(counts, offsets, cursors);
  scatter_kernel<<<N_TOK / 256, 256, 0, stream>>>(topk_idx, topk_w, offsets, cursors,
                                                  assign_token, assign_gate);
  // w1 [E][1024][4096] -> w1b [E][4096][1024]
  transpose_cvt<<<dim3(F_DIM / 32, H_DIM / 32, N_EXP), 256, 0, stream>>>(w1, w1b, H_DIM, F_DIM);
  // w2 [E][4096][1024] -> w2b [E][1024][4096]
  transpose_cvt<<<dim3(H_DIM / 32, F_DIM / 32, N_EXP), 256, 0, stream>>>(w2, w2b, F_DIM, H_DIM);
  gather_kernel<<<NK_ASSIGN / 4, 256, 0, stream>>>(x, assign_token, xg);

  // GEMM1: [cnt_e][1024] @ [4096][1024]^T -> gelu -> h [cnt_e][4096]
  moe_gemm<H_DIM, H_DIM, F_DIM, H_DIM / 32, true>
      <<<dim3(F_DIM / 128, 128, N_EXP), 256, 0, stream>>>(
          xg, w1b, h, nullptr, offsets, assign_token, assign_gate);
  // GEMM2: [cnt_e][4096] @ [1024][4096]^T -> *gate -> atomicAdd out [N][1024]
  moe_gemm<F_DIM, F_DIM, H_DIM, F_DIM / 32, false>
      <<<dim3(H_DIM / 128, 128, N_EXP), 256, 0, stream>>>(
          h, w2b, nullptr, out, offsets, assign_token, assign_gate);

  (void)in_sizes; (void)n_in; (void)ws_size;
}

// Round 2
// 1046.003 us; speedup vs baseline: 1.0393x; 1.0393x over previous
//
#include <hip/hip_runtime.h>
#include <cstdint>
#include <cstddef>

#define H_DIM 1024
#define F_DIM 4096
#define N_EXP 8
#define N_TOK 8192
#define NK_ASSIGN (N_TOK * 2)
#define MAX_MB 24  // max M-blocks/expert = 3072 tokens; actual ~2048±50 (>20 sigma margin)

typedef unsigned short u16;
typedef __attribute__((ext_vector_type(8))) short bf16x8;
typedef __attribute__((ext_vector_type(4))) float f32x4;

// RNE float -> bf16 bits (finite inputs only)
__device__ __forceinline__ u16 f2bf(float f) {
  unsigned int u = __float_as_uint(f);
  u += 0x7fffu + ((u >> 16) & 1u);
  return (u16)(u >> 16);
}

// async global->LDS, 16B per lane. lds ptr MUST be wave-uniform (HW adds lane*16).
__device__ __forceinline__ void load16(const u16* g, u16* l) {
  __builtin_amdgcn_global_load_lds(
      (const __attribute__((address_space(1))) void*)g,
      (__attribute__((address_space(3))) void*)l, 16, 0, 0);
}

// ---------------- router: fp32 logits, top-2, renormalized softmax gates ----
__global__ __launch_bounds__(256) void router_kernel(
    const float* __restrict__ x, const float* __restrict__ rw,
    const float* __restrict__ rb, int* __restrict__ topk_idx,
    float* __restrict__ topk_w, int* __restrict__ counts) {
  const int lane = threadIdx.x & 63;
  const int wid = threadIdx.x >> 6;
  const int t = blockIdx.x * 4 + wid;  // one wave per token
  const float4* xr = (const float4*)(x + (size_t)t * H_DIM);
  float acc[N_EXP];
#pragma unroll
  for (int e = 0; e < N_EXP; ++e) acc[e] = 0.f;
#pragma unroll
  for (int j = 0; j < 4; ++j) {
    float4 xv = xr[j * 64 + lane];
#pragma unroll
    for (int e = 0; e < N_EXP; ++e) {
      float4 wv = ((const float4*)(rw + e * H_DIM))[j * 64 + lane];
      acc[e] += xv.x * wv.x + xv.y * wv.y + xv.z * wv.z + xv.w * wv.w;
    }
  }
#pragma unroll
  for (int off = 32; off > 0; off >>= 1) {
#pragma unroll
    for (int e = 0; e < N_EXP; ++e) acc[e] += __shfl_xor(acc[e], off);
  }
  if (lane == 0) {
    float lg[N_EXP];
#pragma unroll
    for (int e = 0; e < N_EXP; ++e) lg[e] = acc[e] + rb[e];
    int i0 = 0;
    float b0 = lg[0];
#pragma unroll
    for (int e = 1; e < N_EXP; ++e)
      if (lg[e] > b0) { b0 = lg[e]; i0 = e; }  // strict > : lowest index wins ties
    int i1 = -1;
    float b1 = -3.4e38f;
#pragma unroll
    for (int e = 0; e < N_EXP; ++e)
      if (e != i0 && lg[e] > b1) { b1 = lg[e]; i1 = e; }
    float w0 = 1.f / (1.f + __expf(b1 - b0));  // p0/(p0+p1)
    topk_idx[2 * t] = i0;
    topk_idx[2 * t + 1] = i1;
    topk_w[2 * t] = w0;
    topk_w[2 * t + 1] = 1.f - w0;
    atomicAdd(&counts[i0], 1);
    atomicAdd(&counts[i1], 1);
  }
}

// ---------------- tiny exclusive scan over 8 counts --------------------------
__global__ void scan_kernel(const int* __restrict__ counts,
                            int* __restrict__ offsets,
                            int* __restrict__ cursors) {
  if (threadIdx.x == 0) {
    int s = 0;
    for (int e = 0; e < N_EXP; ++e) {
      offsets[e] = s;
      s += counts[e];
      cursors[e] = 0;
    }
    offsets[N_EXP] = s;  // == 16384
  }
}

// ---------------- scatter token assignments into expert segments -------------
__global__ __launch_bounds__(256) void scatter_kernel(
    const int* __restrict__ topk_idx, const float* __restrict__ topk_w,
    const int* __restrict__ offsets, int* __restrict__ cursors,
    int* __restrict__ assign_token, float* __restrict__ assign_gate,
    int* __restrict__ slot_of) {
  int t = blockIdx.x * 256 + threadIdx.x;
  if (t >= N_TOK) return;
#pragma unroll
  for (int k = 0; k < 2; ++k) {
    int e = topk_idx[2 * t + k];
    int pos = offsets[e] + atomicAdd(&cursors[e], 1);
    assign_token[pos] = t;
    assign_gate[pos] = topk_w[2 * t + k];
    slot_of[2 * t + k] = pos;  // inverse map for combine
  }
}

// ---------------- fp32 [E][R][C] -> bf16 [E][C][R] (transpose + convert) -----
// 64x64 tile / 256 threads. float4 coalesced reads; LDS [r][c] stride 66
// (ushort2 writes: 2-way bank = free; b16 column reads: 4-way = 1.58x);
// 16B global writes in 128B-per-row segments.
__global__ __launch_bounds__(256) void transpose_cvt(
    const float* __restrict__ in, u16* __restrict__ out, int R, int C) {
  __shared__ u16 lds[64 * 66];
  const int e = blockIdx.z;
  const float* ip = in + (size_t)e * R * C;
  u16* op = out + (size_t)e * R * C;
  const int c0 = blockIdx.x * 64, r0 = blockIdx.y * 64;
  const int tid = threadIdx.x;
  const int tx = tid & 15, ty = tid >> 4;
#pragma unroll
  for (int i = 0; i < 4; ++i) {
    const int r = ty + i * 16;
    float4 v = *(const float4*)(ip + (size_t)(r0 + r) * C + c0 + tx * 4);
    ushort2 u01, u23;
    u01.x = f2bf(v.x); u01.y = f2bf(v.y);
    u23.x = f2bf(v.z); u23.y = f2bf(v.w);
    *(ushort2*)&lds[r * 66 + tx * 4] = u01;
    *(ushort2*)&lds[r * 66 + tx * 4 + 2] = u23;
  }
  __syncthreads();
  const int lane = tid & 63, wid = tid >> 6;
  const int r8 = lane & 7;
#pragma unroll
  for (int s = 0; s < 2; ++s) {
    const int c = s * 32 + wid * 8 + (lane >> 3);
    union { u16 u[8]; uint4 q; } pk;
#pragma unroll
    for (int k = 0; k < 8; ++k) pk.u[k] = lds[(r8 * 8 + k) * 66 + c];
    *(uint4*)(op + (size_t)(c0 + c) * R + r0 + r8 * 8) = pk.q;
  }
}

// ---------------- gather tokens -> compacted bf16 A ([slot][H]) --------------
__global__ __launch_bounds__(256) void gather_kernel(
    const float* __restrict__ x, const int* __restrict__ assign_token,
    u16* __restrict__ xg) {
  const int lane = threadIdx.x & 63;
  const int s = blockIdx.x * 4 + (threadIdx.x >> 6);  // one wave per slot
  const int t = assign_token[s];
  const float4* xr = (const float4*)(x + (size_t)t * H_DIM);
  u16* o = xg + (size_t)s * H_DIM;
#pragma unroll
  for (int j = 0; j < 4; ++j) {
    float4 v = xr[j * 64 + lane];
    ushort4 u;
    u.x = f2bf(v.x); u.y = f2bf(v.y); u.z = f2bf(v.z); u.w = f2bf(v.w);
    *(ushort4*)(o + (size_t)(j * 64 + lane) * 4) = u;
  }
}

// ---------------- grouped GEMM: C[M][N] = A[M][K] * B[N][K]^T ---------------
// 128x128 tile, BK=32, 4 waves, each wave 4x4 of 16x16x32 bf16 MFMA.
// FIRST:  A=xg, B=w1b, epilogue = tanh-gelu -> bf16 store to h
// !FIRST: A=h,  B=w2b, epilogue = *gate, plain fp32 store to y_slot[slot][H]
template <int LDA, int LDB, int LDC, int KITERS, bool FIRST>
__global__ __launch_bounds__(256) void moe_gemm(
    const u16* __restrict__ Abase, const u16* __restrict__ Bbase,
    u16* __restrict__ hout, float* __restrict__ yout,
    const int* __restrict__ offsets, const float* __restrict__ assign_gate) {
  __shared__ __align__(16) u16 As[128 * 32];
  __shared__ __align__(16) u16 Bs[128 * 32];
  const int e = blockIdx.z;
  const int row0 = offsets[e];
  const int cnt = offsets[e + 1] - row0;
  const int mbase = blockIdx.y * 128;
  if (mbase >= cnt) return;  // block-uniform early exit
  const int mrem = cnt - mbase;
  const int n0 = blockIdx.x * 128;
  const int tid = threadIdx.x;
  const int lane = tid & 63;
  const int wid = tid >> 6;
  const int wm = wid & 1, wn = wid >> 1;
  const u16* A = Abase + (size_t)(row0 + mbase) * LDA;
  const u16* B = Bbase + (size_t)e * ((size_t)H_DIM * F_DIM);
  const int row16 = lane & 15, quad = lane >> 4;
  const int srow = lane >> 2;        // staging: row within 16-row chunk
  const int scol = (lane & 3) * 8;   // staging: k-col (elements)

  f32x4 acc[4][4];
#pragma unroll
  for (int i = 0; i < 4; ++i)
#pragma unroll
    for (int j = 0; j < 4; ++j)
#pragma unroll
      for (int r = 0; r < 4; ++r) acc[i][j][r] = 0.f;

  for (int kt = 0; kt < KITERS; ++kt) {
    const int k0 = kt * 32;
#pragma unroll
    for (int i = 0; i < 2; ++i) {
      const int c = wid * 2 + i;           // chunk 0..7 (16 rows x 64B each)
      const int r = c * 16 + srow;
      const int ra = min(r, mrem - 1);     // clamp: stay inside valid A rows
      load16(A + (size_t)ra * LDA + (k0 + scol), &As[c * 512]);
      load16(B + (size_t)(n0 + r) * LDB + (k0 + scol), &Bs[c * 512]);
    }
    __syncthreads();  // drains vmcnt -> LDS tiles complete
    bf16x8 av[4], bv[4];
#pragma unroll
    for (int mi = 0; mi < 4; ++mi)
      av[mi] = *(const bf16x8*)&As[(wm * 64 + mi * 16 + row16) * 32 + quad * 8];
#pragma unroll
    for (int ni = 0; ni < 4; ++ni)
      bv[ni] = *(const bf16x8*)&Bs[(wn * 64 + ni * 16 + row16) * 32 + quad * 8];
#pragma unroll
    for (int mi = 0; mi < 4; ++mi)
#pragma unroll
      for (int ni = 0; ni < 4; ++ni)
        acc[mi][ni] =
            __builtin_amdgcn_mfma_f32_16x16x32_bf16(av[mi], bv[ni], acc[mi][ni], 0, 0, 0);
    __syncthreads();
  }

  // C/D layout: col = lane&15 (n), row = quad*4 + reg (m)
  if (FIRST) {
    u16* Cp = hout + (size_t)(row0 + mbase) * LDC + n0;
#pragma unroll
    for (int mi = 0; mi < 4; ++mi) {
#pragma unroll
      for (int r = 0; r < 4; ++r) {
        const int lm = wm * 64 + mi * 16 + quad * 4 + r;
        if (lm < mrem) {
#pragma unroll
          for (int ni = 0; ni < 4; ++ni) {
            float v = acc[mi][ni][r];
            // tanh-approx gelu via sigmoid: v * sigmoid(2*sqrt(2/pi)*(v+0.044715v^3))
            float t = v * (0.7978845608028654f + 0.0356774081363f * v * v);
            v = v / (1.f + __expf(-2.f * t));
            Cp[(size_t)lm * LDC + (wn * 64 + ni * 16 + row16)] = f2bf(v);
          }
        }
      }
    }
  } else {
#pragma unroll
    for (int mi = 0; mi < 4; ++mi) {
#pragma unroll
      for (int r = 0; r < 4; ++r) {
        const int lm = wm * 64 + mi * 16 + quad * 4 + r;
        if (lm < mrem) {
          const int slot = row0 + mbase + lm;
          const float g = assign_gate[slot];
          float* orow = yout + (size_t)slot * LDC + n0;
#pragma unroll
          for (int ni = 0; ni < 4; ++ni)
            orow[wn * 64 + ni * 16 + row16] = acc[mi][ni][r] * g;
        }
      }
    }
  }
}

// ---------------- combine: out[t] = y_slot[s0] + y_slot[s1] ------------------
__global__ __launch_bounds__(256) void combine_kernel(
    const float* __restrict__ ys, const int* __restrict__ slot_of,
    float* __restrict__ out) {
  const int t = blockIdx.x;
  const int s0 = slot_of[2 * t], s1 = slot_of[2 * t + 1];
  const int i = threadIdx.x;
  float4 a = ((const float4*)(ys + (size_t)s0 * H_DIM))[i];
  float4 b = ((const float4*)(ys + (size_t)s1 * H_DIM))[i];
  float4 o;
  o.x = a.x + b.x; o.y = a.y + b.y; o.z = a.z + b.z; o.w = a.w + b.w;
  ((float4*)(out + (size_t)t * H_DIM))[i] = o;
}

extern "C" void kernel_launch(void* const* d_in, const int* in_sizes, int n_in,
                              void* d_out, int out_size, void* d_ws, size_t ws_size,
                              hipStream_t stream) {
  const float* x = (const float*)d_in[0];
  const float* rw = (const float*)d_in[1];
  const float* rb = (const float*)d_in[2];
  const float* w1 = (const float*)d_in[3];
  const float* w2 = (const float*)d_in[4];
  float* out = (float*)d_out;

  char* ws = (char*)d_ws;
  // workspace layout (~302.4 MB total)
  u16* w1b = (u16*)(ws);                        // [E][F][H] bf16   67,108,864 B
  float* y_slot = (float*)(ws);                 // [16384][H] fp32 -- ALIASES w1b
                                                // (w1b dead after GEMM1; GEMM2 writes here)
  u16* w2b = (u16*)(ws + 67108864);             // [E][H][F] bf16   67,108,864 B
  u16* xg = (u16*)(ws + 134217728);             // [16384][H] bf16  33,554,432 B
  u16* h = (u16*)(ws + 167772160);              // [16384][F] bf16 134,217,728 B
  char* meta = ws + 301989888;
  int* counts = (int*)(meta + 0);
  int* cursors = (int*)(meta + 32);
  int* offsets = (int*)(meta + 64);             // 9 ints
  int* topk_idx = (int*)(meta + 128);           // 16384 ints
  float* topk_w = (float*)(meta + 128 + 65536);
  int* assign_token = (int*)(meta + 128 + 131072);
  float* assign_gate = (float*)(meta + 128 + 196608);
  int* slot_of = (int*)(meta + 128 + 262144);

  hipMemsetAsync(counts, 0, 64, stream);  // counts + cursors

  router_kernel<<<N_TOK / 4, 256, 0, stream>>>(x, rw, rb, topk_idx, topk_w, counts);
  scan_kernel<<<1, 64, 0, stream>>>(counts, offsets, cursors);
  scatter_kernel<<<N_TOK / 256, 256, 0, stream>>>(topk_idx, topk_w, offsets, cursors,
                                                  assign_token, assign_gate, slot_of);
  // w1 [E][1024][4096] -> w1b [E][4096][1024]
  transpose_cvt<<<dim3(F_DIM / 64, H_DIM / 64, N_EXP), 256, 0, stream>>>(w1, w1b, H_DIM, F_DIM);
  // w2 [E][4096][1024] -> w2b [E][1024][4096]
  transpose_cvt<<<dim3(H_DIM / 64, F_DIM / 64, N_EXP), 256, 0, stream>>>(w2, w2b, F_DIM, H_DIM);
  gather_kernel<<<NK_ASSIGN / 4, 256, 0, stream>>>(x, assign_token, xg);

  // GEMM1: [cnt_e][1024] @ [4096][1024]^T -> gelu -> h [cnt_e][4096]
  moe_gemm<H_DIM, H_DIM, F_DIM, H_DIM / 32, true>
      <<<dim3(F_DIM / 128, MAX_MB, N_EXP), 256, 0, stream>>>(
          xg, w1b, h, nullptr, offsets, assign_gate);
  // GEMM2: [cnt_e][4096] @ [1024][4096]^T -> *gate -> y_slot [16384][1024]
  moe_gemm<F_DIM, F_DIM, H_DIM, F_DIM / 32, false>
      <<<dim3(H_DIM / 128, MAX_MB, N_EXP), 256, 0, stream>>>(
          h, w2b, nullptr, y_slot, offsets, assign_gate);
  // out[t] = y_slot[slot0(t)] + y_slot[slot1(t)]
  combine_kernel<<<N_TOK, 256, 0, stream>>>(y_slot, slot_of, out);

  (void)in_sizes; (void)n_in; (void)ws_size;
}